// Round 4
// baseline (636.928 us; speedup 1.0000x reference)
//
#include <hip/hip_runtime.h>
#include <stdint.h>

// Problem constants (B=8, T=4096, Zc=512, D=256, K=8192)
#define M_TOT 32768
#define ZC 512
#define DD 256
#define KCODES 8192
#define NGRAN 512            // KCODES / 16 codes per granule
#define MARGIN 0.15f         // >2x hard fp16-error bound + storage rounding (validated R2/R3)
#define NBUCKET 256

typedef _Float16 half8   __attribute__((ext_vector_type(8)));
typedef _Float16 half2v  __attribute__((ext_vector_type(2)));
typedef float    float4v __attribute__((ext_vector_type(4)));
typedef float    float16v __attribute__((ext_vector_type(16)));

// Workspace layout (bytes)
#define OFF_H     0ull                  // h fp32: 32 MB
#define OFF_CBT   33554432ull           // cbt fp16 tiled: 4 MB
#define OFF_WTH   37748736ull           // Wt_hi fp16 tiled: 512 KB
#define OFF_WTL   38273024ull           // Wt_lo fp16 tiled: 512 KB
#define OFF_HH    38797312ull           // hh: 128 KB
#define OFF_EE    38928384ull           // ee: 32 KB
#define OFF_SMIN  38961152ull           // smin_T fp16 [NGRAN][M_TOT]: 32 MB
#define OFF_LOSSP 72515584ull           // loss buckets

static __device__ __forceinline__ int pkmin(int a, int b) {
    half2v x = __builtin_bit_cast(half2v, a);
    half2v y = __builtin_bit_cast(half2v, b);
    half2v r;
    r.x = (x.x < y.x) ? x.x : y.x;
    r.y = (x.y < y.y) ? x.y : y.y;
    return __builtin_bit_cast(int, r);
}

// DPP lane-permute (VALU pipe, no LDS): quad_perm/mirrors within 16-lane rows
template <int CTRL>
static __device__ __forceinline__ int dpp_mov(int x) {
    return __builtin_amdgcn_update_dpp(x, x, CTRL, 0xf, 0xf, false);
}
// 16-lane min-reduce of packed half2: after this, every lane in each 16-lane
// group holds the group min.
static __device__ __forceinline__ int pkmin16(int v) {
    v = pkmin(v, dpp_mov<0xB1>(v));   // quad_perm(1,0,3,2)  ~ xor1
    v = pkmin(v, dpp_mov<0x4E>(v));   // quad_perm(2,3,0,1)  ~ xor2
    v = pkmin(v, dpp_mov<0x141>(v));  // row_half_mirror      ~ fold octs
    v = pkmin(v, dpp_mov<0x140>(v));  // row_mirror           ~ fold 16
    return v;
}

// ---------------------------------------------------------------------------
// Prep W: split-fp16 (hi+lo) of W[512][256], stored MFMA-B-tiled:
// off(n,k) = ((n>>5)*64 + (k>>3))*256 + (n&31)*8 + (k&7)
// ---------------------------------------------------------------------------
__global__ __launch_bounds__(256) void k_prep_w(const float* __restrict__ W,
                                                _Float16* __restrict__ wt_hi,
                                                _Float16* __restrict__ wt_lo) {
    const int idx = blockIdx.x * 256 + threadIdx.x;  // 131072
    const int n = idx & 255, k = idx >> 8;
    const float v = W[(size_t)k * DD + n];
    const _Float16 hi = (_Float16)v;
    const _Float16 lo = (_Float16)(v - (float)hi);
    const int off = (((n >> 5) * 64 + (k >> 3)) << 8) + ((n & 31) << 3) + (k & 7);
    wt_hi[off] = hi;
    wt_lo[off] = lo;
}

// ---------------------------------------------------------------------------
// K1: h = x@W + b via split-fp16 MFMA (3 terms: hi*hi + hi*lo + lo*hi).
// Block: 64 rows x 256 cols (full D). 4 waves 2x2, wave = 32x128 (1x4 frags
// of 32x32x16). A (x) staged hi/lo in tiled LDS; B direct global (tiled Wt).
// ---------------------------------------------------------------------------
__global__ __launch_bounds__(256) void k_gemm1(const float* __restrict__ x,
                                               const _Float16* __restrict__ wt_hi,
                                               const _Float16* __restrict__ wt_lo,
                                               const float* __restrict__ b,
                                               float* __restrict__ h) {
    __shared__ _Float16 sH[64 * 64];  // tiled [mblk2][kg8][32][8]
    __shared__ _Float16 sL[64 * 64];
    const int tid = threadIdx.x, lane = tid & 63, w = tid >> 6;
    const int wy = w >> 1, wx = w & 1;
    const int m0 = blockIdx.x * 64;

    float16v acc[4];
#pragma unroll
    for (int j = 0; j < 4; ++j) acc[j] = (float16v)(0.0f);

    for (int kb = 0; kb < ZC; kb += 64) {
        __syncthreads();
        {
            const int m = tid & 63;
            const int kp = tid >> 6;  // 0..3
#pragma unroll
            for (int i2 = 0; i2 < 2; ++i2) {
                const int kg = kp * 2 + i2;
                const float* src = x + (size_t)(m0 + m) * ZC + kb + kg * 8;
                float4v v0 = *(const float4v*)src;
                float4v v1 = *(const float4v*)(src + 4);
                half8 hi, lo;
                float vv[8] = {v0.x, v0.y, v0.z, v0.w, v1.x, v1.y, v1.z, v1.w};
#pragma unroll
                for (int j = 0; j < 8; ++j) {
                    hi[j] = (_Float16)vv[j];
                    lo[j] = (_Float16)(vv[j] - (float)hi[j]);
                }
                const int off = (((m >> 5) * 8 + kg) << 8) + ((m & 31) << 3);
                *(half8*)&sH[off] = hi;
                *(half8*)&sL[off] = lo;
            }
        }
        __syncthreads();
#pragma unroll
        for (int s = 0; s < 4; ++s) {
            const int S = (kb >> 4) + s;  // global k-step
            half8 ah = *(const half8*)&sH[((wy * 8 + 2 * s) << 8) + lane * 8];
            half8 al = *(const half8*)&sL[((wy * 8 + 2 * s) << 8) + lane * 8];
#pragma unroll
            for (int nf = 0; nf < 4; ++nf) {
                const int nblk = wx * 4 + nf;
                const size_t boff = ((size_t)(nblk * 64 + 2 * S) << 8) + lane * 8;
                half8 bh = *(const half8*)&wt_hi[boff];
                half8 bl = *(const half8*)&wt_lo[boff];
                acc[nf] = __builtin_amdgcn_mfma_f32_32x32x16_f16(ah, bh, acc[nf], 0, 0, 0);
                acc[nf] = __builtin_amdgcn_mfma_f32_32x32x16_f16(ah, bl, acc[nf], 0, 0, 0);
                acc[nf] = __builtin_amdgcn_mfma_f32_32x32x16_f16(al, bh, acc[nf], 0, 0, 0);
            }
        }
    }
    // Epilogue: C layout col=lane&31, row=(r&3)+8*(r>>2)+4*(lane>>5)
#pragma unroll
    for (int nf = 0; nf < 4; ++nf) {
        const int col = wx * 128 + nf * 32 + (lane & 31);
        const float bias = b[col];
#pragma unroll
        for (int r = 0; r < 16; ++r) {
            const int row = m0 + wy * 32 + (r & 3) + 8 * (r >> 2) + 4 * (lane >> 5);
            h[(size_t)row * DD + col] = acc[nf][r] + bias;
        }
    }
}

// ---------------------------------------------------------------------------
// Row squared-norms of h, wave-per-row
// ---------------------------------------------------------------------------
__global__ __launch_bounds__(256) void k_rownorm(const float* __restrict__ a,
                                                 float* __restrict__ out) {
    const int w = threadIdx.x >> 6, lane = threadIdx.x & 63;
    const int row = blockIdx.x * 4 + w;
    float4v v = *(const float4v*)&a[(size_t)row * DD + lane * 4];
    float s = v.x * v.x + v.y * v.y + v.z * v.z + v.w * v.w;
#pragma unroll
    for (int off = 32; off; off >>= 1) s += __shfl_down(s, off);
    if (lane == 0) out[row] = s;
}

// ---------------------------------------------------------------------------
// Prep codebook: fp16 MFMA-B-tiled copy + squared norms + zero loss buckets.
// cbt off(code,k) = ((code>>5)*32 + (k>>3))*256 + (code&31)*8 + (k&7)
// ---------------------------------------------------------------------------
__global__ __launch_bounds__(256) void k_prep_cb(const float* __restrict__ cb,
                                                 _Float16* __restrict__ cbt,
                                                 float* __restrict__ ee,
                                                 float* __restrict__ loss_part) {
    if (blockIdx.x == 0) loss_part[threadIdx.x] = 0.0f;
    const int lane = threadIdx.x & 63, w = threadIdx.x >> 6;
    const int code = blockIdx.x * 4 + w;
    float4v v = *(const float4v*)&cb[(size_t)code * DD + lane * 4];
    half2v p0, p1;
    p0.x = (_Float16)v.x; p0.y = (_Float16)v.y;
    p1.x = (_Float16)v.z; p1.y = (_Float16)v.w;
    // k = lane*4 -> kg = lane>>1, (k&7) = (lane&1)*4
    const size_t off = ((size_t)(((code >> 5) * 32 + (lane >> 1))) << 8) +
                       ((code & 31) << 3) + ((lane & 1) << 2);
    *(half2v*)&cbt[off] = p0;
    *(half2v*)&cbt[off + 2] = p1;
    float s = v.x * v.x + v.y * v.y + v.z * v.z + v.w * v.w;
#pragma unroll
    for (int o = 32; o; o >>= 1) s += __shfl_down(s, o);
    if (lane == 0) ee[code] = s;
}

// ---------------------------------------------------------------------------
// Phase 1: barrier-free N-streaming distance kernel.
// Block: 128 rows x 4096 codes (half the codebook). A (h, fp32->fp16 inline)
// staged once in tiled LDS; B direct global from cbt (1KB contiguous/inst).
// 32x32x16 MFMA, 2x4 frags/wave. Epilogue: DPP pk-min per 16-code granule,
// s = ee - 2*dot, stored fp16 to smin_T[granule][row] (ushort4 = 4 rows).
// ---------------------------------------------------------------------------
__global__ __launch_bounds__(256, 2) void k_dist(const float* __restrict__ h,
                                                 const _Float16* __restrict__ cbt,
                                                 const float* __restrict__ ee,
                                                 _Float16* __restrict__ smin) {
    __shared__ _Float16 sA[128 * 256];  // tiled [mblk4][kg32][32][8] = 64 KB
    const int tid = threadIdx.x;
    const int lane = tid & 63, w = tid >> 6;
    const int wm = w >> 1, wn = w & 1;
    const int m0 = blockIdx.y * 128;
    const int tn_base = blockIdx.x * 32;  // 32 N-tiles of 128 codes

    // Stage A: h fp32 -> fp16, tiled. Coalesced global reads.
    for (int i = 0; i < 16; ++i) {
        const int idx = i * 256 + tid;  // 4096 (m,kg) pairs
        const int m = idx >> 5, kg = idx & 31;
        const float* src = h + (size_t)(m0 + m) * DD + kg * 8;
        float4v v0 = *(const float4v*)src;
        float4v v1 = *(const float4v*)(src + 4);
        half8 hv;
        float vv[8] = {v0.x, v0.y, v0.z, v0.w, v1.x, v1.y, v1.z, v1.w};
#pragma unroll
        for (int j = 0; j < 8; ++j) hv[j] = (_Float16)vv[j];
        *(half8*)&sA[(((m >> 5) * 32 + kg) << 8) + ((m & 31) << 3)] = hv;
    }
    __syncthreads();

    for (int tn = tn_base + wn; tn < tn_base + 32; tn += 2) {
        float16v acc[2][4];
#pragma unroll
        for (int i = 0; i < 2; ++i)
#pragma unroll
            for (int j = 0; j < 4; ++j) acc[i][j] = (float16v)(0.0f);

#pragma unroll
        for (int s = 0; s < 16; ++s) {
            half8 a0 = *(const half8*)&sA[(((wm * 2 + 0) * 32 + 2 * s) << 8) + lane * 8];
            half8 a1 = *(const half8*)&sA[(((wm * 2 + 1) * 32 + 2 * s) << 8) + lane * 8];
            half8 b0 = *(const half8*)&cbt[((size_t)((tn * 4 + 0) * 32 + 2 * s) << 8) + lane * 8];
            half8 b1 = *(const half8*)&cbt[((size_t)((tn * 4 + 1) * 32 + 2 * s) << 8) + lane * 8];
            half8 b2 = *(const half8*)&cbt[((size_t)((tn * 4 + 2) * 32 + 2 * s) << 8) + lane * 8];
            half8 b3 = *(const half8*)&cbt[((size_t)((tn * 4 + 3) * 32 + 2 * s) << 8) + lane * 8];
            acc[0][0] = __builtin_amdgcn_mfma_f32_32x32x16_f16(a0, b0, acc[0][0], 0, 0, 0);
            acc[1][0] = __builtin_amdgcn_mfma_f32_32x32x16_f16(a1, b0, acc[1][0], 0, 0, 0);
            acc[0][1] = __builtin_amdgcn_mfma_f32_32x32x16_f16(a0, b1, acc[0][1], 0, 0, 0);
            acc[1][1] = __builtin_amdgcn_mfma_f32_32x32x16_f16(a1, b1, acc[1][1], 0, 0, 0);
            acc[0][2] = __builtin_amdgcn_mfma_f32_32x32x16_f16(a0, b2, acc[0][2], 0, 0, 0);
            acc[1][2] = __builtin_amdgcn_mfma_f32_32x32x16_f16(a1, b2, acc[1][2], 0, 0, 0);
            acc[0][3] = __builtin_amdgcn_mfma_f32_32x32x16_f16(a0, b3, acc[0][3], 0, 0, 0);
            acc[1][3] = __builtin_amdgcn_mfma_f32_32x32x16_f16(a1, b3, acc[1][3], 0, 0, 0);
        }

        // Epilogue: s = ee - 2*dot; DPP min within 16-lane groups (= 16-code
        // granules); writer lanes store ushort4 (4 consecutive rows).
#pragma unroll
        for (int nf = 0; nf < 4; ++nf) {
            const float e = ee[tn * 128 + nf * 32 + (lane & 31)];
            const int g = tn * 8 + nf * 2 + ((lane >> 4) & 1);
#pragma unroll
            for (int mf = 0; mf < 2; ++mf) {
                float16v a = acc[mf][nf];
                int pk[8];
#pragma unroll
                for (int p = 0; p < 8; ++p) {
                    half2v t2;
                    t2.x = (_Float16)(e - 2.0f * a[2 * p]);
                    t2.y = (_Float16)(e - 2.0f * a[2 * p + 1]);
                    pk[p] = pkmin16(__builtin_bit_cast(int, t2));
                }
                const int k = lane & 15;
                if (k < 4) {
                    // pk[2k], pk[2k+1] = rows k*8 .. k*8+3 (4-way select)
                    int lo = (k & 2) ? ((k & 1) ? pk[6] : pk[4])
                                     : ((k & 1) ? pk[2] : pk[0]);
                    int hi = (k & 2) ? ((k & 1) ? pk[7] : pk[5])
                                     : ((k & 1) ? pk[3] : pk[1]);
                    const int row = m0 + wm * 64 + mf * 32 + k * 8 + ((lane >> 5) << 2);
                    int2 st = {lo, hi};
                    *(int2*)&smin[(size_t)g * M_TOT + row] = st;
                }
            }
        }
    }
}

// ---------------------------------------------------------------------------
// Phase 2: wave-per-row. LDS-transpose a 64-row slab of smin_T, then per row:
// min + MARGIN threshold, candidate granules via ballot, exact fp32 rescore
// ((hh+ee)-2*dot, lowest-index tie-break), gather zq, write out, loss.
// ---------------------------------------------------------------------------
__global__ __launch_bounds__(256, 2) void k_select(const float* __restrict__ h,
                                                   const float* __restrict__ cb,
                                                   const float* __restrict__ hh,
                                                   const float* __restrict__ ee,
                                                   const _Float16* __restrict__ smin,
                                                   float* __restrict__ out,
                                                   float* __restrict__ loss_part) {
    __shared__ _Float16 sS[64][512];  // [row][granule] = 64 KB
    const int t = threadIdx.x, lane = t & 63, w = t >> 6;
    const int r0 = blockIdx.x * 64;

    // Transpose-load: thread t handles granules t and t+256.
    for (int gi = t; gi < NGRAN; gi += 256) {
        const _Float16* src = smin + (size_t)gi * M_TOT + r0;
#pragma unroll
        for (int c = 0; c < 8; ++c) {
            half8 v = *(const half8*)(src + c * 8);
#pragma unroll
            for (int j = 0; j < 8; ++j) sS[c * 8 + j][gi] = v[j];
        }
    }
    __syncthreads();

    float lossacc = 0.0f;
    for (int i = 0; i < 16; ++i) {
        const int row = r0 + w * 16 + i;
        float4v hv = *(const float4v*)&h[(size_t)row * DD + lane * 4];
        half8 sm = *(const half8*)&sS[w * 16 + i][lane * 8];
        float vmin = 1e30f;
        float sv[8];
#pragma unroll
        for (int j = 0; j < 8; ++j) {
            sv[j] = (float)sm[j];
            vmin = fminf(vmin, sv[j]);
        }
        float m2 = vmin;
#pragma unroll
        for (int o = 32; o; o >>= 1) m2 = fminf(m2, __shfl_xor(m2, o));
        const float thr = m2 + MARGIN;
        unsigned flags = 0;
#pragma unroll
        for (int j = 0; j < 8; ++j)
            if (sv[j] <= thr) flags |= (1u << j);

        unsigned long long act = __ballot(flags != 0);
        unsigned long long bestk = ~0ull;
        const float hhv = hh[row];
        while (act) {
            const int ln = __ffsll((long long)act) - 1;
            act &= act - 1;
            unsigned fl = (unsigned)__shfl((int)flags, ln);
            while (fl) {
                const int j = __ffs(fl) - 1;
                fl &= fl - 1;
                const int g = ln * 8 + j;
#pragma unroll
                for (int c = 0; c < 16; ++c) {
                    const int code = g * 16 + c;
                    float4v cv = *(const float4v*)&cb[(size_t)code * DD + lane * 4];
                    float s = hv.x * cv.x + hv.y * cv.y + hv.z * cv.z + hv.w * cv.w;
#pragma unroll
                    for (int o = 32; o; o >>= 1) s += __shfl_xor(s, o);
                    const float d = (hhv + ee[code]) - 2.0f * s;  // reference formula
                    const unsigned bts = __float_as_uint(d);
                    const unsigned mb =
                        bts ^ (unsigned)(((int)bts >> 31) | 0x80000000);
                    const unsigned long long key =
                        ((unsigned long long)mb << 32) | (unsigned)code;
                    if (key < bestk) bestk = key;
                }
            }
        }
        // bestk is lane-uniform. Gather + output + loss.
        const unsigned best = (unsigned)(bestk & 0xffffffffull);
        float4v cv = *(const float4v*)&cb[(size_t)best * DD + lane * 4];
        *(float4v*)&out[(size_t)row * DD + lane * 4] = cv;
        const float dx = cv.x - hv.x, dy = cv.y - hv.y;
        const float dz = cv.z - hv.z, dw = cv.w - hv.w;
        lossacc += dx * dx + dy * dy + dz * dz + dw * dw;
    }
#pragma unroll
    for (int o = 32; o; o >>= 1) lossacc += __shfl_xor(lossacc, o);
    if (lane == 0)
        atomicAdd(&loss_part[(blockIdx.x * 4 + w) & (NBUCKET - 1)], lossacc);
}

__global__ __launch_bounds__(256) void k_final(const float* __restrict__ loss_part,
                                               float* __restrict__ out) {
    const int t = threadIdx.x;
    float s = loss_part[t];
#pragma unroll
    for (int off = 32; off; off >>= 1) s += __shfl_down(s, off);
    __shared__ float wsum[4];
    if ((t & 63) == 0) wsum[t >> 6] = s;
    __syncthreads();
    if (t == 0)
        out[0] = 1.25f * ((wsum[0] + wsum[1]) + (wsum[2] + wsum[3]))
                 / (float)(M_TOT * DD);  // BETA*mean + mean
}

// ---------------------------------------------------------------------------
extern "C" void kernel_launch(void* const* d_in, const int* in_sizes, int n_in,
                              void* d_out, int out_size, void* d_ws, size_t ws_size,
                              hipStream_t stream) {
    const float* x  = (const float*)d_in[0];
    const float* W  = (const float*)d_in[1];
    const float* b  = (const float*)d_in[2];
    const float* cb = (const float*)d_in[3];
    float* out = (float*)d_out;

    char* ws = (char*)d_ws;
    float* h        = (float*)(ws + OFF_H);
    _Float16* cbt   = (_Float16*)(ws + OFF_CBT);
    _Float16* wt_hi = (_Float16*)(ws + OFF_WTH);
    _Float16* wt_lo = (_Float16*)(ws + OFF_WTL);
    float* hh       = (float*)(ws + OFF_HH);
    float* ee       = (float*)(ws + OFF_EE);
    _Float16* smin  = (_Float16*)(ws + OFF_SMIN);
    float* loss_part = (float*)(ws + OFF_LOSSP);

    hipLaunchKernelGGL(k_prep_w, dim3(512), dim3(256), 0, stream, W, wt_hi, wt_lo);
    hipLaunchKernelGGL(k_prep_cb, dim3(KCODES / 4), dim3(256), 0, stream,
                       cb, cbt, ee, loss_part);
    hipLaunchKernelGGL(k_gemm1, dim3(M_TOT / 64), dim3(256), 0, stream,
                       x, wt_hi, wt_lo, b, h);
    hipLaunchKernelGGL(k_rownorm, dim3(M_TOT / 4), dim3(256), 0, stream, h, hh);
    hipLaunchKernelGGL(k_dist, dim3(2, M_TOT / 128), dim3(256), 0, stream,
                       h, cbt, ee, smin);
    hipLaunchKernelGGL(k_select, dim3(M_TOT / 64), dim3(256), 0, stream,
                       h, cb, hh, ee, smin, out, loss_part);
    hipLaunchKernelGGL(k_final, dim3(1), dim3(256), 0, stream,
                       loss_part, out + (size_t)M_TOT * DD);
}

// Round 6
// 369.442 us; speedup vs baseline: 1.7240x; 1.7240x over previous
//
#include <hip/hip_runtime.h>
#include <stdint.h>

// Problem constants (B=8, T=4096, Zc=512, D=256, K=8192)
#define M_TOT 32768
#define ZC 512
#define DD 256
#define KCODES 8192
#define NGRAN 512            // KCODES / 16 codes per granule
#define MARGIN 0.15f         // >2x hard fp16-error bound (validated R2/R3/R4)
#define NBUCKET 256

typedef _Float16 half8   __attribute__((ext_vector_type(8)));
typedef _Float16 half2v  __attribute__((ext_vector_type(2)));
typedef float    float4v __attribute__((ext_vector_type(4)));
typedef float    float16v __attribute__((ext_vector_type(16)));

// Workspace layout (bytes). wt_hi/wt_lo overlap smin: prep_w/gemm1 finish
// before k_dist writes smin (stream-ordered, every launch identical).
#define OFF_H     0ull                  // h fp32: 32 MB
#define OFF_HT    33554432ull           // ht fp16 tiled: 16 MB
#define OFF_CBT   50331648ull           // cbt fp16 tiled: 4 MB
#define OFF_HH    54525952ull           // hh: 128 KB
#define OFF_EE    54657024ull           // ee: 32 KB
#define OFF_LOSSP 54689792ull           // loss buckets: 1 KB
#define OFF_SMIN  54691840ull           // smin_T fp16 [NGRAN][M_TOT]: 32 MB
#define OFF_WTH   OFF_SMIN              // Wt_hi fp16 tiled: 512 KB (overlap)
#define OFF_WTL   (OFF_SMIN + 524288ull) // Wt_lo fp16 tiled: 512 KB (overlap)

// async global->LDS, 16B per lane, LDS dst = wave-uniform base + lane*16
#define ASYNC_CP16(gp, lp)                                                     \
  __builtin_amdgcn_global_load_lds(                                            \
      (const __attribute__((address_space(1))) void*)(gp),                     \
      (__attribute__((address_space(3))) void*)(lp), 16, 0, 0)

// ---------------------------------------------------------------------------
// Prep W: split-fp16 (hi+lo) of W[512][256], stored MFMA-B-tiled:
// off(n,k) = ((n>>5)*64 + (k>>3))*256 + (n&31)*8 + (k&7)
// ---------------------------------------------------------------------------
__global__ __launch_bounds__(256) void k_prep_w(const float* __restrict__ W,
                                                _Float16* __restrict__ wt_hi,
                                                _Float16* __restrict__ wt_lo) {
    const int idx = blockIdx.x * 256 + threadIdx.x;  // 131072
    const int n = idx & 255, k = idx >> 8;
    const float v = W[(size_t)k * DD + n];
    const _Float16 hi = (_Float16)v;
    const _Float16 lo = (_Float16)(v - (float)hi);
    const int off = (((n >> 5) * 64 + (k >> 3)) << 8) + ((n & 31) << 3) + (k & 7);
    wt_hi[off] = hi;
    wt_lo[off] = lo;
}

// ---------------------------------------------------------------------------
// K1: h = x@W + b via split-fp16 MFMA (hi*hi + hi*lo + lo*hi). Verified R4.
// ---------------------------------------------------------------------------
__global__ __launch_bounds__(256) void k_gemm1(const float* __restrict__ x,
                                               const _Float16* __restrict__ wt_hi,
                                               const _Float16* __restrict__ wt_lo,
                                               const float* __restrict__ b,
                                               float* __restrict__ h) {
    __shared__ _Float16 sH[64 * 64];  // tiled [mblk2][kg8][32][8]
    __shared__ _Float16 sL[64 * 64];
    const int tid = threadIdx.x, lane = tid & 63, w = tid >> 6;
    const int wy = w >> 1, wx = w & 1;
    const int m0 = blockIdx.x * 64;

    float16v acc[4];
#pragma unroll
    for (int j = 0; j < 4; ++j) acc[j] = (float16v)(0.0f);

    for (int kb = 0; kb < ZC; kb += 64) {
        __syncthreads();
        {
            const int m = tid & 63;
            const int kp = tid >> 6;  // 0..3
#pragma unroll
            for (int i2 = 0; i2 < 2; ++i2) {
                const int kg = kp * 2 + i2;
                const float* src = x + (size_t)(m0 + m) * ZC + kb + kg * 8;
                float4v v0 = *(const float4v*)src;
                float4v v1 = *(const float4v*)(src + 4);
                half8 hi, lo;
                float vv[8] = {v0.x, v0.y, v0.z, v0.w, v1.x, v1.y, v1.z, v1.w};
#pragma unroll
                for (int j = 0; j < 8; ++j) {
                    hi[j] = (_Float16)vv[j];
                    lo[j] = (_Float16)(vv[j] - (float)hi[j]);
                }
                const int off = (((m >> 5) * 8 + kg) << 8) + ((m & 31) << 3);
                *(half8*)&sH[off] = hi;
                *(half8*)&sL[off] = lo;
            }
        }
        __syncthreads();
#pragma unroll
        for (int s = 0; s < 4; ++s) {
            const int S = (kb >> 4) + s;  // global k-step
            half8 ah = *(const half8*)&sH[((wy * 8 + 2 * s) << 8) + lane * 8];
            half8 al = *(const half8*)&sL[((wy * 8 + 2 * s) << 8) + lane * 8];
#pragma unroll
            for (int nf = 0; nf < 4; ++nf) {
                const int nblk = wx * 4 + nf;
                const size_t boff = ((size_t)(nblk * 64 + 2 * S) << 8) + lane * 8;
                half8 bh = *(const half8*)&wt_hi[boff];
                half8 bl = *(const half8*)&wt_lo[boff];
                acc[nf] = __builtin_amdgcn_mfma_f32_32x32x16_f16(ah, bh, acc[nf], 0, 0, 0);
                acc[nf] = __builtin_amdgcn_mfma_f32_32x32x16_f16(ah, bl, acc[nf], 0, 0, 0);
                acc[nf] = __builtin_amdgcn_mfma_f32_32x32x16_f16(al, bh, acc[nf], 0, 0, 0);
            }
        }
    }
    // Epilogue: C layout col=lane&31, row=(r&3)+8*(r>>2)+4*(lane>>5)
#pragma unroll
    for (int nf = 0; nf < 4; ++nf) {
        const int col = wx * 128 + nf * 32 + (lane & 31);
        const float bias = b[col];
#pragma unroll
        for (int r = 0; r < 16; ++r) {
            const int row = m0 + wy * 32 + (r & 3) + 8 * (r >> 2) + 4 * (lane >> 5);
            h[(size_t)row * DD + col] = acc[nf][r] + bias;
        }
    }
}

// ---------------------------------------------------------------------------
// Prep h: fp16 MFMA-tiled copy + row squared-norms (folds old k_rownorm).
// ht off(row,k) = ((row>>5)*32 + (k>>3))*256 + (row&31)*8 + (k&7)
// ---------------------------------------------------------------------------
__global__ __launch_bounds__(256) void k_prep_h(const float* __restrict__ h,
                                                _Float16* __restrict__ ht,
                                                float* __restrict__ hh) {
    const int lane = threadIdx.x & 63, w = threadIdx.x >> 6;
    const int row = blockIdx.x * 4 + w;
    float4v v = *(const float4v*)&h[(size_t)row * DD + lane * 4];
    half2v p0, p1;
    p0.x = (_Float16)v.x; p0.y = (_Float16)v.y;
    p1.x = (_Float16)v.z; p1.y = (_Float16)v.w;
    const size_t off = ((size_t)((row >> 5) * 32 + (lane >> 1)) << 8) +
                       ((row & 31) << 3) + ((lane & 1) << 2);
    *(half2v*)&ht[off] = p0;
    *(half2v*)&ht[off + 2] = p1;
    float s = v.x * v.x + v.y * v.y + v.z * v.z + v.w * v.w;
#pragma unroll
    for (int o = 32; o; o >>= 1) s += __shfl_down(s, o);
    if (lane == 0) hh[row] = s;
}

// ---------------------------------------------------------------------------
// Prep codebook: fp16 MFMA-tiled copy + squared norms + zero loss buckets.
// ---------------------------------------------------------------------------
__global__ __launch_bounds__(256) void k_prep_cb(const float* __restrict__ cb,
                                                 _Float16* __restrict__ cbt,
                                                 float* __restrict__ ee,
                                                 float* __restrict__ loss_part) {
    if (blockIdx.x == 0) loss_part[threadIdx.x] = 0.0f;
    const int lane = threadIdx.x & 63, w = threadIdx.x >> 6;
    const int code = blockIdx.x * 4 + w;
    float4v v = *(const float4v*)&cb[(size_t)code * DD + lane * 4];
    half2v p0, p1;
    p0.x = (_Float16)v.x; p0.y = (_Float16)v.y;
    p1.x = (_Float16)v.z; p1.y = (_Float16)v.w;
    const size_t off = ((size_t)((code >> 5) * 32 + (lane >> 1)) << 8) +
                       ((code & 31) << 3) + ((lane & 1) << 2);
    *(half2v*)&cbt[off] = p0;
    *(half2v*)&cbt[off + 2] = p1;
    float s = v.x * v.x + v.y * v.y + v.z * v.z + v.w * v.w;
#pragma unroll
    for (int o = 32; o; o >>= 1) s += __shfl_down(s, o);
    if (lane == 0) ee[code] = s;
}

// ---------------------------------------------------------------------------
// Phase 1 distance kernel, A-in-registers.
// Block: 256 codes x 1024 rows (8 stages of 128 rows). Wave: 64 codes
// (2 A-frags, full K=256 in VGPRs = 128 regs, loaded once) x 128 rows.
// Stage: h-tile 128x256 fp16 = 64 KB LDS (tiled, conflict-free), via
// global_load_lds from pre-tiled ht. 2 MFMA per b128 LDS read -> DS pipe
// ~64 B/cyc/CU demand vs ~85 supply: MFMA-bound.
// ee folded as a 17th k-substep: A_ext[c][0]=ee[c], B_ext[r][0]=-0.5,
// so s = ee - 2*dot = -2*acc. Epilogue: per-granule max of acc (8 regs) +
// one shfl_xor(32), store fp16 to smin_T[granule][row].
// A-frag k-mapping: lane L holds k = (L>>5)*8 + j  =>  byte addr must use
// lane*8 = csel*256 + lw*8 halves (R5 bug: csel*512 read the wrong k-slice).
// ---------------------------------------------------------------------------
__global__ __launch_bounds__(256, 2) void k_dist(const _Float16* __restrict__ ht,
                                                 const _Float16* __restrict__ cbt,
                                                 const float* __restrict__ ee,
                                                 _Float16* __restrict__ smin) {
    __shared__ _Float16 sB[128 * 256];  // 64 KB, tiled [rowblk4][kg32][32][8]
    const int tid = threadIdx.x, lane = tid & 63, w = tid >> 6;
    const int lw = lane & 31, csel = lane >> 5;
    const int bx = blockIdx.x;  // 256-code split
    const int by = blockIdx.y;  // 1024-row split

    // Load A: 2 mfrags x 16 k-substeps, each half8 (codes in lanes&31).
    half8 afr[2][16];
    const size_t lo = (size_t)lane * 8;  // = csel*256 + lw*8 (kg = 2s+csel)
#pragma unroll
    for (int mi = 0; mi < 2; ++mi) {
        const _Float16* base = cbt + (size_t)(bx * 8 + w * 2 + mi) * 8192;
#pragma unroll
        for (int s = 0; s < 16; ++s)
            afr[mi][s] = *(const half8*)(base + s * 512 + lo);
    }
    // ee-folding ext frags
    half8 aext[2], bext;
#pragma unroll
    for (int j = 0; j < 8; ++j) bext[j] = (_Float16)0.f;
    if (csel == 0) bext[0] = (_Float16)(-0.5f);
#pragma unroll
    for (int mi = 0; mi < 2; ++mi) {
        const float e = ee[bx * 256 + w * 64 + mi * 32 + lw];
#pragma unroll
        for (int j = 0; j < 8; ++j) aext[mi][j] = (_Float16)0.f;
        if (csel == 0) aext[mi][0] = (_Float16)e;
    }

    for (int it = 0; it < 8; ++it) {
        const int r0 = (by * 8 + it) * 128;
        __syncthreads();  // prior stage's consumers done before overwrite
        {
            // 64 KB contiguous tiled chunk of ht; wave w copies 16 KB.
            const _Float16* g = ht + (size_t)r0 * 256 + w * 8192 + lane * 8;
            char* l = (char*)sB + w * 16384;
#pragma unroll
            for (int i = 0; i < 16; ++i)
                ASYNC_CP16(g + i * 512, l + i * 1024);
        }
        __syncthreads();  // staged data visible

#pragma unroll 1
        for (int nj = 0; nj < 4; ++nj) {
            float16v acc0 = (float16v)(0.f), acc1 = (float16v)(0.f);
#pragma unroll
            for (int s = 0; s < 16; ++s) {
                half8 bf = *(const half8*)&sB[(size_t)((nj * 32 + 2 * s + csel) << 8) + lw * 8];
                acc0 = __builtin_amdgcn_mfma_f32_32x32x16_f16(afr[0][s], bf, acc0, 0, 0, 0);
                acc1 = __builtin_amdgcn_mfma_f32_32x32x16_f16(afr[1][s], bf, acc1, 0, 0, 0);
            }
            acc0 = __builtin_amdgcn_mfma_f32_32x32x16_f16(aext[0], bext, acc0, 0, 0, 0);
            acc1 = __builtin_amdgcn_mfma_f32_32x32x16_f16(aext[1], bext, acc1, 0, 0, 0);

            // Epilogue: s = -2*acc; min(s) = -2*max(acc).
            // C row (code) = (r&3)+8*(r>>2)+4*csel: granule0 = r 0..7, g1 = r 8..15.
            float g0a = acc0[0], g1a = acc0[8];
            float g0b = acc1[0], g1b = acc1[8];
#pragma unroll
            for (int r = 1; r < 8; ++r) {
                g0a = fmaxf(g0a, acc0[r]);  g1a = fmaxf(g1a, acc0[8 + r]);
                g0b = fmaxf(g0b, acc1[r]);  g1b = fmaxf(g1b, acc1[8 + r]);
            }
            g0a = fmaxf(g0a, __shfl_xor(g0a, 32));
            g1a = fmaxf(g1a, __shfl_xor(g1a, 32));
            g0b = fmaxf(g0b, __shfl_xor(g0b, 32));
            g1b = fmaxf(g1b, __shfl_xor(g1b, 32));
            if (lane < 32) {
                const int row = r0 + nj * 32 + lane;
                const int gb = bx * 16 + w * 4;
                smin[(size_t)(gb + 0) * M_TOT + row] = (_Float16)(-2.f * g0a);
                smin[(size_t)(gb + 1) * M_TOT + row] = (_Float16)(-2.f * g1a);
                smin[(size_t)(gb + 2) * M_TOT + row] = (_Float16)(-2.f * g0b);
                smin[(size_t)(gb + 3) * M_TOT + row] = (_Float16)(-2.f * g1b);
            }
        }
    }
}

// ---------------------------------------------------------------------------
// Phase 2: wave-per-row (verified R4). LDS-transpose 64-row slab of smin_T,
// margin-filter granules, exact fp32 rescore ((hh+ee)-2*dot, lowest-index
// tie-break), gather zq, write out, bucketized loss.
// ---------------------------------------------------------------------------
__global__ __launch_bounds__(256, 2) void k_select(const float* __restrict__ h,
                                                   const float* __restrict__ cb,
                                                   const float* __restrict__ hh,
                                                   const float* __restrict__ ee,
                                                   const _Float16* __restrict__ smin,
                                                   float* __restrict__ out,
                                                   float* __restrict__ loss_part) {
    __shared__ _Float16 sS[64][512];  // [row][granule] = 64 KB
    const int t = threadIdx.x, lane = t & 63, w = t >> 6;
    const int r0 = blockIdx.x * 64;

    for (int gi = t; gi < NGRAN; gi += 256) {
        const _Float16* src = smin + (size_t)gi * M_TOT + r0;
#pragma unroll
        for (int c = 0; c < 8; ++c) {
            half8 v = *(const half8*)(src + c * 8);
#pragma unroll
            for (int j = 0; j < 8; ++j) sS[c * 8 + j][gi] = v[j];
        }
    }
    __syncthreads();

    float lossacc = 0.0f;
    for (int i = 0; i < 16; ++i) {
        const int row = r0 + w * 16 + i;
        float4v hv = *(const float4v*)&h[(size_t)row * DD + lane * 4];
        half8 sm = *(const half8*)&sS[w * 16 + i][lane * 8];
        float vmin = 1e30f;
        float sv[8];
#pragma unroll
        for (int j = 0; j < 8; ++j) {
            sv[j] = (float)sm[j];
            vmin = fminf(vmin, sv[j]);
        }
        float m2 = vmin;
#pragma unroll
        for (int o = 32; o; o >>= 1) m2 = fminf(m2, __shfl_xor(m2, o));
        const float thr = m2 + MARGIN;
        unsigned flags = 0;
#pragma unroll
        for (int j = 0; j < 8; ++j)
            if (sv[j] <= thr) flags |= (1u << j);

        unsigned long long act = __ballot(flags != 0);
        unsigned long long bestk = ~0ull;
        const float hhv = hh[row];
        while (act) {
            const int ln = __ffsll((long long)act) - 1;
            act &= act - 1;
            unsigned fl = (unsigned)__shfl((int)flags, ln);
            while (fl) {
                const int j = __ffs(fl) - 1;
                fl &= fl - 1;
                const int g = ln * 8 + j;
#pragma unroll
                for (int c = 0; c < 16; ++c) {
                    const int code = g * 16 + c;
                    float4v cv = *(const float4v*)&cb[(size_t)code * DD + lane * 4];
                    float s = hv.x * cv.x + hv.y * cv.y + hv.z * cv.z + hv.w * cv.w;
#pragma unroll
                    for (int o = 32; o; o >>= 1) s += __shfl_xor(s, o);
                    const float d = (hhv + ee[code]) - 2.0f * s;  // reference formula
                    const unsigned bts = __float_as_uint(d);
                    const unsigned mb =
                        bts ^ (unsigned)(((int)bts >> 31) | 0x80000000);
                    const unsigned long long key =
                        ((unsigned long long)mb << 32) | (unsigned)code;
                    if (key < bestk) bestk = key;
                }
            }
        }
        const unsigned best = (unsigned)(bestk & 0xffffffffull);
        float4v cv = *(const float4v*)&cb[(size_t)best * DD + lane * 4];
        *(float4v*)&out[(size_t)row * DD + lane * 4] = cv;
        const float dx = cv.x - hv.x, dy = cv.y - hv.y;
        const float dz = cv.z - hv.z, dw = cv.w - hv.w;
        lossacc += dx * dx + dy * dy + dz * dz + dw * dw;
    }
#pragma unroll
    for (int o = 32; o; o >>= 1) lossacc += __shfl_xor(lossacc, o);
    if (lane == 0)
        atomicAdd(&loss_part[(blockIdx.x * 4 + w) & (NBUCKET - 1)], lossacc);
}

__global__ __launch_bounds__(256) void k_final(const float* __restrict__ loss_part,
                                               float* __restrict__ out) {
    const int t = threadIdx.x;
    float s = loss_part[t];
#pragma unroll
    for (int off = 32; off; off >>= 1) s += __shfl_down(s, off);
    __shared__ float wsum[4];
    if ((t & 63) == 0) wsum[t >> 6] = s;
    __syncthreads();
    if (t == 0)
        out[0] = 1.25f * ((wsum[0] + wsum[1]) + (wsum[2] + wsum[3]))
                 / (float)(M_TOT * DD);  // BETA*mean + mean
}

// ---------------------------------------------------------------------------
extern "C" void kernel_launch(void* const* d_in, const int* in_sizes, int n_in,
                              void* d_out, int out_size, void* d_ws, size_t ws_size,
                              hipStream_t stream) {
    const float* x  = (const float*)d_in[0];
    const float* W  = (const float*)d_in[1];
    const float* b  = (const float*)d_in[2];
    const float* cb = (const float*)d_in[3];
    float* out = (float*)d_out;

    char* ws = (char*)d_ws;
    float* h        = (float*)(ws + OFF_H);
    _Float16* ht    = (_Float16*)(ws + OFF_HT);
    _Float16* cbt   = (_Float16*)(ws + OFF_CBT);
    _Float16* wt_hi = (_Float16*)(ws + OFF_WTH);
    _Float16* wt_lo = (_Float16*)(ws + OFF_WTL);
    float* hh       = (float*)(ws + OFF_HH);
    float* ee       = (float*)(ws + OFF_EE);
    _Float16* smin  = (_Float16*)(ws + OFF_SMIN);
    float* loss_part = (float*)(ws + OFF_LOSSP);

    hipLaunchKernelGGL(k_prep_w, dim3(512), dim3(256), 0, stream, W, wt_hi, wt_lo);
    hipLaunchKernelGGL(k_prep_cb, dim3(KCODES / 4), dim3(256), 0, stream,
                       cb, cbt, ee, loss_part);
    hipLaunchKernelGGL(k_gemm1, dim3(M_TOT / 64), dim3(256), 0, stream,
                       x, wt_hi, wt_lo, b, h);
    hipLaunchKernelGGL(k_prep_h, dim3(M_TOT / 4), dim3(256), 0, stream,
                       h, ht, hh);
    hipLaunchKernelGGL(k_dist, dim3(KCODES / 256, M_TOT / 1024), dim3(256),
                       0, stream, ht, cbt, ee, smin);
    hipLaunchKernelGGL(k_select, dim3(M_TOT / 64), dim3(256), 0, stream,
                       h, cb, hh, ee, smin, out, loss_part);
    hipLaunchKernelGGL(k_final, dim3(1), dim3(256), 0, stream,
                       loss_part, out + (size_t)M_TOT * DD);
}